// Round 8
// baseline (148.843 us; speedup 1.0000x reference)
//
#include <hip/hip_runtime.h>
#include <hip/hip_bf16.h>
#include <math.h>

#define NCC 80
#define BINS 16
#define NCH 144   // 4*BINS+NC
#define NB 16
#define NG 32
#define NA 8400
#define HW0 6400
#define HW1 1600
#define HW2 400
#define TOPKK 10
#define EPSF 1e-9f
#define MAXC 832              // candidate capacity per gt (worst case 677)
#define MAXFG (NB*NG*TOPKK)   // 5120
#define NMASK (NB*NA)         // 134400
#define NRES 528              // k_resolve blocks (33 x 16)
#define DEC_BLOCKS 525        // decode part of k_main
#define FOCAL_BLOCKS 2625     // focal part of k_main
#define MAIN_BLOCKS (DEC_BLOCKS + FOCAL_BLOCKS)

__device__ __forceinline__ void anchor_geom(int n, float& cx, float& cy, float& st){
    if(n < HW0){ int y=n/80, x=n-y*80; st=8.f; cx=(x+0.5f)*8.f; cy=(y+0.5f)*8.f; }
    else if(n < HW0+HW1){ int m=n-HW0; int y=m/40, x=m-y*40; st=16.f; cx=(x+0.5f)*16.f; cy=(y+0.5f)*16.f; }
    else { int m=n-(HW0+HW1); int y=m/20, x=m-y*20; st=32.f; cx=(x+0.5f)*32.f; cy=(y+0.5f)*32.f; }
}

__device__ __forceinline__ const float* level_base(const float* p0, const float* p1, const float* p2,
                                                   int b, int n, int& m, int& hw){
    if(n < HW0){ m=n; hw=HW0; return p0 + (size_t)b*NCH*HW0; }
    if(n < HW0+HW1){ m=n-HW0; hw=HW1; return p1 + (size_t)b*NCH*HW1; }
    m=n-(HW0+HW1); hw=HW2; return p2 + (size_t)b*NCH*HW2;
}

__device__ __forceinline__ float iou_gp(float gx1,float gy1,float gx2,float gy2,
                                        float px1,float py1,float px2,float py2){
    float ltx = fmaxf(gx1, px1), lty = fmaxf(gy1, py1);
    float rbx = fminf(gx2, px2), rby = fminf(gy2, py2);
    float w = fmaxf(rbx-ltx, 0.f), h = fmaxf(rby-lty, 0.f);
    float inter = w*h;
    float ag = (gx2-gx1)*(gy2-gy1);
    float ap = fmaxf(px2-px1,0.f)*fmaxf(py2-py1,0.f);
    return inter/(ag+ap-inter+EPSF);
}

// focal term for target=0: 0.75 * p^2 * ce0(x).  MUST be identical math everywhere.
__device__ __forceinline__ float focal0(float x, float& p, float& ce0){
    float ax = fabsf(x);
    float e  = __expf(-ax);
    float r  = 1.f/(1.f+e);            // sigmoid(|x|)
    p   = (x >= 0.f) ? r : 1.f - r;    // sigmoid(x)
    ce0 = fmaxf(x,0.f) + __logf(1.f+e);
    return 0.75f*p*p*ce0;
}

// ------- kernel 1: fused [DFL decode + lse store + ws init | focal t=0 stream] -------
__global__ __launch_bounds__(256) void k_main(const float* __restrict__ p0, const float* __restrict__ p1,
                                              const float* __restrict__ p2, float* __restrict__ boxc,
                                              float* __restrict__ lsev,
                                              unsigned* __restrict__ maskg, float* __restrict__ amax,
                                              float* __restrict__ omax, int* __restrict__ cnt,
                                              float* __restrict__ pcls){
    int tid = threadIdx.x;
    if(blockIdx.x < DEC_BLOCKS){
        // ---- decode path (+ zero-init of small state) ----
        int l = blockIdx.x*256 + tid;            // exactly NMASK threads
        maskg[l] = 0u;
        if(l < NB*NG){ amax[l] = 0.f; omax[l] = 0.f; }
        if(l == 0) *cnt = 0;
        int q = l % 2100;
        int j = (l / 2100) & 3;
        int b = l / 8400;
        const float* pl; int hw, m, n0, D; float st;
        if(q < 1600){ pl=p0; hw=HW0; m=4*q;        n0=m;         D=80; st=8.f; }
        else if(q < 2000){ pl=p1; hw=HW1; m=4*(q-1600); n0=HW0+m;     D=40; st=16.f; }
        else { pl=p2; hw=HW2; m=4*(q-2000); n0=HW0+HW1+m; D=20; st=32.f; }
        const float* ch = pl + ((size_t)b*NCH + j*BINS)*hw + m;
        float4 v[BINS];
        float4 mx = make_float4(-1e30f,-1e30f,-1e30f,-1e30f);
        #pragma unroll
        for(int k=0;k<BINS;k++){
            v[k] = *(const float4*)(ch + (size_t)k*hw);
            mx.x=fmaxf(mx.x,v[k].x); mx.y=fmaxf(mx.y,v[k].y);
            mx.z=fmaxf(mx.z,v[k].z); mx.w=fmaxf(mx.w,v[k].w);
        }
        float4 s = make_float4(0,0,0,0), acc = make_float4(0,0,0,0);
        #pragma unroll
        for(int k=0;k<BINS;k++){
            float fk=(float)k; float e;
            e=__expf(v[k].x-mx.x); s.x+=e; acc.x+=e*fk;
            e=__expf(v[k].y-mx.y); s.y+=e; acc.y+=e*fk;
            e=__expf(v[k].z-mx.z); s.z+=e; acc.z+=e*fk;
            e=__expf(v[k].w-mx.w); s.w+=e; acc.w+=e*fk;
        }
        // log-sum-exp per anchor (for DFL loss later)
        float4 lse = make_float4(mx.x+__logf(s.x), mx.y+__logf(s.y),
                                 mx.z+__logf(s.z), mx.w+__logf(s.w));
        *(float4*)(lsev + (size_t)j*NB*NA + (size_t)b*NA + n0) = lse;
        float4 d = make_float4(acc.x/s.x*st, acc.y/s.y*st, acc.z/s.z*st, acc.w/s.w*st);
        int row = m / D, col = m - row*D;
        float cy = (row+0.5f)*st;
        float cx0=(col+0.5f)*st, cx1=(col+1.5f)*st, cx2=(col+2.5f)*st, cx3=(col+3.5f)*st;
        float4 o;
        if(j==0)      o = make_float4(cx0-d.x, cx1-d.y, cx2-d.z, cx3-d.w);
        else if(j==1) o = make_float4(cy -d.x, cy -d.y, cy -d.z, cy -d.w);
        else if(j==2) o = make_float4(cx0+d.x, cx1+d.y, cx2+d.z, cx3+d.w);
        else          o = make_float4(cy +d.x, cy +d.y, cy +d.z, cy +d.w);
        *(float4*)(boxc + (size_t)j*NB*NA + (size_t)b*NA + n0) = o;
    } else {
        // ---- focal t=0 streaming path ----
        __shared__ float s4[4];
        int blk = blockIdx.x - DEC_BLOCKS;
        int t = blk*256 + tid;                   // 672000 threads
        float acc = 0.f;
        #pragma unroll
        for(int it=0; it<4; ++it){
            int i4 = t + it*672000;
            const float4* src;
            if(i4 < 2048000){
                int b = i4 / 128000; int r = i4 - b*128000;
                src = (const float4*)(p0 + (size_t)b*921600 + 409600) + r;
            } else if(i4 < 2560000){
                int j = i4 - 2048000; int b = j / 32000; int r = j - b*32000;
                src = (const float4*)(p1 + (size_t)b*230400 + 102400) + r;
            } else {
                int j = i4 - 2560000; int b = j / 8000; int r = j - b*8000;
                src = (const float4*)(p2 + (size_t)b*57600 + 25600) + r;
            }
            float4 x4 = *src;
            float p, c;
            acc += focal0(x4.x, p, c);
            acc += focal0(x4.y, p, c);
            acc += focal0(x4.z, p, c);
            acc += focal0(x4.w, p, c);
        }
        #pragma unroll
        for(int off=32; off; off>>=1) acc += __shfl_down(acc, off);
        if((tid&63)==0) s4[tid>>6] = acc;
        __syncthreads();
        if(tid==0) pcls[blk] = s4[0]+s4[1]+s4[2]+s4[3];
    }
}

// ------- kernel 2: TAL top-10 per (b,g), one BLOCK per gt -------
__global__ __launch_bounds__(256) void k_assign(const float* __restrict__ p0, const float* __restrict__ p1,
                                                const float* __restrict__ p2, const float* __restrict__ boxc,
                                                const float* __restrict__ gtb, const int* __restrict__ gtl,
                                                unsigned* __restrict__ maskg){
    __shared__ float metric[MAXC];
    __shared__ int   candn[MAXC];
    __shared__ float rv[4]; __shared__ int ri[4];
    __shared__ float sbest;
    int g = blockIdx.x, b = blockIdx.y, tid = threadIdx.x;
    const float* gb = gtb + ((size_t)b*NG + g)*4;
    float gx1=gb[0], gy1=gb[1], gx2=gb[2], gy2=gb[3];
    int label = gtl[b*NG+g];
    const float* bx1 = boxc + (size_t)b*NA;
    const float* by1 = bx1 + (size_t)NB*NA;
    const float* bx2 = by1 + (size_t)NB*NA;
    const float* by2 = bx2 + (size_t)NB*NA;

    int xs[3], ys[3], nxv[3], cc[3];
    #pragma unroll
    for(int lvl=0; lvl<3; lvl++){
        float s = (float)(8<<lvl); int D = 80>>lvl;
        int x0 = max(0, (int)floorf(gx1/s - 0.5f));
        int x1 = min(D-1, (int)ceilf (gx2/s - 0.5f));
        int y0 = max(0, (int)floorf(gy1/s - 0.5f));
        int y1 = min(D-1, (int)ceilf (gy2/s - 0.5f));
        xs[lvl]=x0; ys[lvl]=y0;
        nxv[lvl]=max(0, x1-x0+1);
        int nyv=max(0, y1-y0+1);
        cc[lvl]=nxv[lvl]*nyv;
    }
    int t0 = cc[0], t01 = cc[0]+cc[1], total = t01+cc[2];

    for(int c=tid; c<total; c+=256){
        int lvl, rel;
        if(c < t0){ lvl=0; rel=c; }
        else if(c < t01){ lvl=1; rel=c-t0; }
        else { lvl=2; rel=c-t01; }
        int yy = ys[lvl] + rel / nxv[lvl];
        int xx = xs[lvl] + rel % nxv[lvl];
        int D = 80>>lvl; float s = (float)(8<<lvl);
        int off = (lvl==0)?0:((lvl==1)?HW0:(HW0+HW1));
        int n = off + yy*D + xx;
        float cx = (xx+0.5f)*s, cy = (yy+0.5f)*s;
        float met = 0.f;
        if((cx>gx1)&&(cx<gx2)&&(cy>gy1)&&(cy<gy2)){
            float ov = iou_gp(gx1,gy1,gx2,gy2, bx1[n],by1[n],bx2[n],by2[n]);
            int m,hw; const float* base = level_base(p0,p1,p2,b,n,m,hw);
            float x = base[(size_t)(4*BINS+label)*hw + m];
            float sg = 1.f/(1.f+__expf(-x));
            float o2 = ov*ov;
            met = sqrtf(sg)*(o2*o2*o2);
        }
        metric[c] = met; candn[c] = n;
    }
    __syncthreads();

    for(int k=0;k<TOPKK;k++){
        float bv = -1.f; int bi = 0x7fffffff;
        for(int c=tid; c<total; c+=256){
            float v = metric[c];
            if(v > bv){ bv=v; bi=c; }           // ascending scan keeps lowest candidate idx
        }
        #pragma unroll
        for(int o=1; o<64; o<<=1){
            float ov = __shfl_xor(bv, o);
            int   oi = __shfl_xor(bi, o);
            if(ov > bv || (ov == bv && oi < bi)){ bv=ov; bi=oi; }
        }
        if((tid&63)==0){ rv[tid>>6]=bv; ri[tid>>6]=bi; }
        __syncthreads();
        if(tid==0){
            float fb=rv[0]; int fi=ri[0];
            #pragma unroll
            for(int w=1; w<4; w++)
                if(rv[w]>fb || (rv[w]==fb && ri[w]<fi)){ fb=rv[w]; fi=ri[w]; }
            sbest = fb;
            if(fb > EPSF){
                metric[fi] = -1.f;
                atomicOr(&maskg[(size_t)b*NA + candn[fi]], 1u<<g);
            }
        }
        __syncthreads();
        if(sbest <= EPSF) break;                // uniform
    }
}

// ------- kernel 3: resolve + CIoU + DFL inline + fg compaction -------
__global__ __launch_bounds__(256) void k_resolve(const float* __restrict__ p0, const float* __restrict__ p1,
                                                 const float* __restrict__ p2, const float* __restrict__ boxc,
                                                 const float* __restrict__ lsev,
                                                 const float* __restrict__ gtb, const int* __restrict__ gtl,
                                                 const unsigned* __restrict__ maskg,
                                                 float* __restrict__ amax, float* __restrict__ omax,
                                                 int* __restrict__ cnt, int* __restrict__ fgbg,
                                                 float* __restrict__ fgalign, float* __restrict__ fgx,
                                                 float* __restrict__ piou, float* __restrict__ pdfl){
    __shared__ float sgt[NG*4];
    __shared__ int wcnt[4];
    __shared__ int sbase;
    __shared__ float siou[4], sdfl[4];
    int tid = threadIdx.x; int b = blockIdx.y;
    int wv = tid >> 6, lane = tid & 63;
    if(tid < NG*4) sgt[tid] = gtb[(size_t)b*NG*4 + tid];
    __syncthreads();
    int n = blockIdx.x*256 + tid;
    size_t bn = (size_t)b*NA + n;
    unsigned mask = (n < NA) ? maskg[bn] : 0u;
    bool fg = (mask != 0u);

    int match = 0; float av = 0.f, x = 0.f;
    float iou_l = 0.f, dfl_l = 0.f;
    if(fg){
        float px1 = boxc[bn], py1 = boxc[(size_t)NB*NA+bn],
              px2 = boxc[2*(size_t)NB*NA+bn], py2 = boxc[3*(size_t)NB*NA+bn];
        float ov;
        if(__popc(mask) > 1){
            float best = -1.f; int bi = 0;
            for(int g=0; g<NG; g++){
                float o = iou_gp(sgt[g*4],sgt[g*4+1],sgt[g*4+2],sgt[g*4+3],px1,py1,px2,py2);
                if(o > best){ best=o; bi=g; }   // strict > : first max == jnp.argmax
            }
            match = bi; ov = best;
        } else {
            match = __ffs(mask)-1;
            ov = iou_gp(sgt[match*4],sgt[match*4+1],sgt[match*4+2],sgt[match*4+3],px1,py1,px2,py2);
        }
        int label = gtl[b*NG+match];
        int m,hw; const float* base = level_base(p0,p1,p2,b,n,m,hw);
        x = base[(size_t)(4*BINS+label)*hw + m];
        float sg = 1.f/(1.f+__expf(-x));
        float ov2 = ov*ov;
        av = sqrtf(sg)*(ov2*ov2*ov2);
        atomicMax((int*)&amax[b*NG+match], __float_as_int(av));
        atomicMax((int*)&omax[b*NG+match], __float_as_int(ov));
        // ---- CIoU (target box = matched gt) ----
        float tx1=sgt[match*4], ty1=sgt[match*4+1], tx2=sgt[match*4+2], ty2=sgt[match*4+3];
        float w1=px2-px1, h1=py2-py1, w2=tx2-tx1, h2=ty2-ty1;
        float inter = fmaxf(fminf(px2,tx2)-fmaxf(px1,tx1),0.f) *
                      fmaxf(fminf(py2,ty2)-fmaxf(py1,ty1),0.f);
        float uni = w1*h1 + w2*h2 - inter + EPSF;
        float iou = inter/uni;
        float cwd = fmaxf(px2,tx2)-fminf(px1,tx1);
        float chd = fmaxf(py2,ty2)-fminf(py1,ty1);
        float c2 = cwd*cwd + chd*chd + EPSF;
        float ddx = px1+px2-tx1-tx2, ddy = py1+py2-ty1-ty2;
        float rho2 = (ddx*ddx + ddy*ddy)*0.25f;
        float dv = atanf(w2/(h2+EPSF)) - atanf(w1/(h1+EPSF));
        float v = 0.40528473456935108577f*dv*dv;   // 4/pi^2
        float alpha = v/(v - iou + 1.f + EPSF);
        iou_l = 1.f - (iou - rho2/c2 - v*alpha);
        // ---- DFL via precomputed lse + 2 logits per side ----
        float cx,cy,st; anchor_geom(n,cx,cy,st);
        float dt4[4] = { cx-tx1, cy-ty1, tx2-cx, ty2-cy };
        #pragma unroll
        for(int j=0;j<4;j++){
            float d = fminf(fmaxf(dt4[j],0.f)/st, 14.999999f);
            float lo = floorf(d); float a = d-lo;
            int li = (int)lo; int ui = min(li+1, BINS-1);
            float lse = lsev[(size_t)j*NB*NA + bn];
            float xlo = base[(size_t)(j*BINS+li)*hw + m];
            float xup = base[(size_t)(j*BINS+ui)*hw + m];
            dfl_l += -((1.f-a)*(xlo-lse) + a*(xup-lse));
        }
    }
    // fg compaction (ballot, one atomic per block)
    unsigned long long bal = __ballot(fg);
    if(lane==0) wcnt[wv] = __popcll(bal);
    __syncthreads();
    if(tid==0){
        int tot = wcnt[0]+wcnt[1]+wcnt[2]+wcnt[3];
        sbase = tot ? atomicAdd(cnt, tot) : 0;
    }
    __syncthreads();
    if(fg){
        int woff = 0;
        for(int w=0; w<wv; w++) woff += wcnt[w];
        int before = __popcll(bal & ((1ull<<lane)-1ull));
        int pos = sbase + woff + before;
        fgbg[pos]    = b*NG + match;
        fgalign[pos] = av;
        fgx[pos]     = x;
    }
    // block partials for iou/dfl
    #pragma unroll
    for(int o=32; o; o>>=1){
        iou_l += __shfl_down(iou_l, o);
        dfl_l += __shfl_down(dfl_l, o);
    }
    if(lane==0){ siou[wv]=iou_l; sdfl[wv]=dfl_l; }
    __syncthreads();
    if(tid==0){
        int blk = blockIdx.y*33 + blockIdx.x;
        piou[blk] = siou[0]+siou[1]+siou[2]+siou[3];
        pdfl[blk] = sdfl[0]+sdfl[1]+sdfl[2]+sdfl[3];
    }
}

// ------- kernel 4: focal fix over fg items + final reduce + weights -------
__global__ __launch_bounds__(256) void k_final(const float* __restrict__ pcls, const float* __restrict__ piou,
                                               const float* __restrict__ pdfl,
                                               const float* __restrict__ amax, const float* __restrict__ omax,
                                               const int* __restrict__ fgbg, const float* __restrict__ fgalign,
                                               const float* __restrict__ fgx,
                                               const int* __restrict__ cnt, float* __restrict__ out){
    __shared__ float sam[NB*NG], som[NB*NG];
    __shared__ float sa[4], sb[4], sc[4], sd[4];
    int tid = threadIdx.x, wv = tid>>6, lane = tid&63;
    for(int t=tid; t<NB*NG; t+=256){ sam[t]=amax[t]; som[t]=omax[t]; }
    __syncthreads();
    int c = *cnt;
    float A = 0.f, B = 0.f, C = 0.f, D = 0.f;
    for(int t=tid; t<FOCAL_BLOCKS; t+=256) A += pcls[t];
    for(int t=tid; t<NRES; t+=256){ B += piou[t]; C += pdfl[t]; }
    for(int i=tid; i<c; i+=256){
        int bg = fgbg[i];
        float norm = fgalign[i] * som[bg] / (sam[bg] + EPSF);
        float fx = fgx[i];
        float p, ce0;
        float f0 = focal0(fx, p, ce0);
        float cet = ce0 - fx*norm;
        float pt = p*norm + (1.f-p)*(1.f-norm);
        float at = 0.25f*norm + 0.75f*(1.f-norm);
        float om = 1.f-pt;
        D += at*om*om*cet - f0;
    }
    #pragma unroll
    for(int o=32; o; o>>=1){
        A += __shfl_down(A, o);
        B += __shfl_down(B, o);
        C += __shfl_down(C, o);
        D += __shfl_down(D, o);
    }
    if(lane==0){ sa[wv]=A; sb[wv]=B; sc[wv]=C; sd[wv]=D; }
    __syncthreads();
    if(tid==0){
        float a  = sa[0]+sa[1]+sa[2]+sa[3];
        float bb = sb[0]+sb[1]+sb[2]+sb[3];
        float cc = sc[0]+sc[1]+sc[2]+sc[3];
        float dd = sd[0]+sd[1]+sd[2]+sd[3];
        float den = (float)(c > 1 ? c : 1);
        out[0] = 7.5f * bb / den;
        out[1] = 1.5f * cc / den;
        out[2] = 0.5f * (a + dd) / den;
    }
}

extern "C" void kernel_launch(void* const* d_in, const int* in_sizes, int n_in,
                              void* d_out, int out_size, void* d_ws, size_t ws_size,
                              hipStream_t stream) {
    (void)in_sizes; (void)n_in; (void)out_size; (void)ws_size;
    const float* p0  = (const float*)d_in[0];
    const float* p1  = (const float*)d_in[1];
    const float* p2  = (const float*)d_in[2];
    const float* gtb = (const float*)d_in[3];
    const int*   gtl = (const int*)d_in[4];
    float* out = (float*)d_out;

    char* ws = (char*)d_ws;
    const size_t COMP = (size_t)NB*NA*4;          // 537600 B
    size_t off = 0;
    int*      cnt    = (int*)     (ws + off); off += 16;
    float*    amax   = (float*)   (ws + off); off += NB*NG*4;       // 2048
    float*    omax   = (float*)   (ws + off); off += NB*NG*4;
    unsigned* maskg  = (unsigned*)(ws + off); off += COMP;
    float*    boxc   = (float*)   (ws + off); off += 4*COMP;        // SoA x1,y1,x2,y2
    float*    lsev   = (float*)   (ws + off); off += 4*COMP;        // per (j,b,n) log-sum-exp
    int*      fgbg   = (int*)     (ws + off); off += MAXFG*4;
    float*    fgalign= (float*)   (ws + off); off += MAXFG*4;
    float*    fgx    = (float*)   (ws + off); off += MAXFG*4;
    float*    pcls   = (float*)   (ws + off); off += FOCAL_BLOCKS*4;
    float*    piou   = (float*)   (ws + off); off += NRES*4;
    float*    pdfl   = (float*)   (ws + off); off += NRES*4;

    dim3 blk(256);
    k_main   <<<MAIN_BLOCKS,   blk, 0, stream>>>(p0,p1,p2, boxc, lsev, maskg, amax, omax, cnt, pcls);
    k_assign <<<dim3(NG,NB),   blk, 0, stream>>>(p0,p1,p2, boxc, gtb, gtl, maskg);
    k_resolve<<<dim3(33,NB),   blk, 0, stream>>>(p0,p1,p2, boxc, lsev, gtb, gtl, maskg,
                                                 amax, omax, cnt, fgbg, fgalign, fgx, piou, pdfl);
    k_final  <<<1,             blk, 0, stream>>>(pcls, piou, pdfl, amax, omax,
                                                 fgbg, fgalign, fgx, cnt, out);
}

// Round 9
// 143.931 us; speedup vs baseline: 1.0341x; 1.0341x over previous
//
#include <hip/hip_runtime.h>
#include <hip/hip_bf16.h>
#include <math.h>

#define NCC 80
#define BINS 16
#define NCH 144   // 4*BINS+NC
#define NB 16
#define NG 32
#define NA 8400
#define HW0 6400
#define HW1 1600
#define HW2 400
#define TOPKK 10
#define EPSF 1e-9f
#define MAXC 832              // candidate capacity per gt (worst case 677)
#define MAXFG (NB*NG*TOPKK)   // 5120
#define FGB2 20               // k_fg blocks: 5120 threads / 256
#define NMASK (NB*NA)         // 134400
#define DEC_BLOCKS 525        // decode part of k_main
#define FOCAL_BLOCKS 2625     // focal part of k_main
#define MAIN_BLOCKS (DEC_BLOCKS + FOCAL_BLOCKS)

__device__ __forceinline__ void anchor_geom(int n, float& cx, float& cy, float& st){
    if(n < HW0){ int y=n/80, x=n-y*80; st=8.f; cx=(x+0.5f)*8.f; cy=(y+0.5f)*8.f; }
    else if(n < HW0+HW1){ int m=n-HW0; int y=m/40, x=m-y*40; st=16.f; cx=(x+0.5f)*16.f; cy=(y+0.5f)*16.f; }
    else { int m=n-(HW0+HW1); int y=m/20, x=m-y*20; st=32.f; cx=(x+0.5f)*32.f; cy=(y+0.5f)*32.f; }
}

__device__ __forceinline__ const float* level_base(const float* p0, const float* p1, const float* p2,
                                                   int b, int n, int& m, int& hw){
    if(n < HW0){ m=n; hw=HW0; return p0 + (size_t)b*NCH*HW0; }
    if(n < HW0+HW1){ m=n-HW0; hw=HW1; return p1 + (size_t)b*NCH*HW1; }
    m=n-(HW0+HW1); hw=HW2; return p2 + (size_t)b*NCH*HW2;
}

__device__ __forceinline__ float iou_gp(float gx1,float gy1,float gx2,float gy2,
                                        float px1,float py1,float px2,float py2){
    float ltx = fmaxf(gx1, px1), lty = fmaxf(gy1, py1);
    float rbx = fminf(gx2, px2), rby = fminf(gy2, py2);
    float w = fmaxf(rbx-ltx, 0.f), h = fmaxf(rby-lty, 0.f);
    float inter = w*h;
    float ag = (gx2-gx1)*(gy2-gy1);
    float ap = fmaxf(px2-px1,0.f)*fmaxf(py2-py1,0.f);
    return inter/(ag+ap-inter+EPSF);
}

// focal term for target=0: 0.75 * p^2 * ce0(x).  MUST be identical math everywhere.
__device__ __forceinline__ float focal0(float x, float& p, float& ce0){
    float ax = fabsf(x);
    float e  = __expf(-ax);
    float r  = 1.f/(1.f+e);            // sigmoid(|x|)
    p   = (x >= 0.f) ? r : 1.f - r;    // sigmoid(x)
    ce0 = fmaxf(x,0.f) + __logf(1.f+e);
    return 0.75f*p*p*ce0;
}

// ------- kernel 1: fused [DFL decode + lse store + ws init | focal t=0 stream] -------
__global__ __launch_bounds__(256) void k_main(const float* __restrict__ p0, const float* __restrict__ p1,
                                              const float* __restrict__ p2, float* __restrict__ boxc,
                                              float* __restrict__ lsev,
                                              unsigned* __restrict__ maskg, float* __restrict__ amax,
                                              float* __restrict__ omax, int* __restrict__ cnt,
                                              float* __restrict__ pcls){
    int tid = threadIdx.x;
    if(blockIdx.x < DEC_BLOCKS){
        // ---- decode path (+ zero-init of small state) ----
        int l = blockIdx.x*256 + tid;            // exactly NMASK threads
        maskg[l] = 0u;
        if(l < NB*NG){ amax[l] = 0.f; omax[l] = 0.f; }
        if(l == 0) *cnt = 0;
        int q = l % 2100;
        int j = (l / 2100) & 3;
        int b = l / 8400;
        const float* pl; int hw, m, n0, D; float st;
        if(q < 1600){ pl=p0; hw=HW0; m=4*q;        n0=m;         D=80; st=8.f; }
        else if(q < 2000){ pl=p1; hw=HW1; m=4*(q-1600); n0=HW0+m;     D=40; st=16.f; }
        else { pl=p2; hw=HW2; m=4*(q-2000); n0=HW0+HW1+m; D=20; st=32.f; }
        const float* ch = pl + ((size_t)b*NCH + j*BINS)*hw + m;
        float4 v[BINS];
        float4 mx = make_float4(-1e30f,-1e30f,-1e30f,-1e30f);
        #pragma unroll
        for(int k=0;k<BINS;k++){
            v[k] = *(const float4*)(ch + (size_t)k*hw);
            mx.x=fmaxf(mx.x,v[k].x); mx.y=fmaxf(mx.y,v[k].y);
            mx.z=fmaxf(mx.z,v[k].z); mx.w=fmaxf(mx.w,v[k].w);
        }
        float4 s = make_float4(0,0,0,0), acc = make_float4(0,0,0,0);
        #pragma unroll
        for(int k=0;k<BINS;k++){
            float fk=(float)k; float e;
            e=__expf(v[k].x-mx.x); s.x+=e; acc.x+=e*fk;
            e=__expf(v[k].y-mx.y); s.y+=e; acc.y+=e*fk;
            e=__expf(v[k].z-mx.z); s.z+=e; acc.z+=e*fk;
            e=__expf(v[k].w-mx.w); s.w+=e; acc.w+=e*fk;
        }
        // log-sum-exp per anchor (for DFL loss later)
        float4 lse = make_float4(mx.x+__logf(s.x), mx.y+__logf(s.y),
                                 mx.z+__logf(s.z), mx.w+__logf(s.w));
        *(float4*)(lsev + (size_t)j*NB*NA + (size_t)b*NA + n0) = lse;
        float4 d = make_float4(acc.x/s.x*st, acc.y/s.y*st, acc.z/s.z*st, acc.w/s.w*st);
        int row = m / D, col = m - row*D;
        float cy = (row+0.5f)*st;
        float cx0=(col+0.5f)*st, cx1=(col+1.5f)*st, cx2=(col+2.5f)*st, cx3=(col+3.5f)*st;
        float4 o;
        if(j==0)      o = make_float4(cx0-d.x, cx1-d.y, cx2-d.z, cx3-d.w);
        else if(j==1) o = make_float4(cy -d.x, cy -d.y, cy -d.z, cy -d.w);
        else if(j==2) o = make_float4(cx0+d.x, cx1+d.y, cx2+d.z, cx3+d.w);
        else          o = make_float4(cy +d.x, cy +d.y, cy +d.z, cy +d.w);
        *(float4*)(boxc + (size_t)j*NB*NA + (size_t)b*NA + n0) = o;
    } else {
        // ---- focal t=0 streaming path ----
        __shared__ float s4[4];
        int blk = blockIdx.x - DEC_BLOCKS;
        int t = blk*256 + tid;                   // 672000 threads
        float acc = 0.f;
        #pragma unroll
        for(int it=0; it<4; ++it){
            int i4 = t + it*672000;
            const float4* src;
            if(i4 < 2048000){
                int b = i4 / 128000; int r = i4 - b*128000;
                src = (const float4*)(p0 + (size_t)b*921600 + 409600) + r;
            } else if(i4 < 2560000){
                int j = i4 - 2048000; int b = j / 32000; int r = j - b*32000;
                src = (const float4*)(p1 + (size_t)b*230400 + 102400) + r;
            } else {
                int j = i4 - 2560000; int b = j / 8000; int r = j - b*8000;
                src = (const float4*)(p2 + (size_t)b*57600 + 25600) + r;
            }
            float4 x4 = *src;
            float p, c;
            acc += focal0(x4.x, p, c);
            acc += focal0(x4.y, p, c);
            acc += focal0(x4.z, p, c);
            acc += focal0(x4.w, p, c);
        }
        #pragma unroll
        for(int off=32; off; off>>=1) acc += __shfl_down(acc, off);
        if((tid&63)==0) s4[tid>>6] = acc;
        __syncthreads();
        if(tid==0) pcls[blk] = s4[0]+s4[1]+s4[2]+s4[3];
    }
}

// ------- kernel 2: TAL top-10 per (b,g), one BLOCK per gt -------
__global__ __launch_bounds__(256) void k_assign(const float* __restrict__ p0, const float* __restrict__ p1,
                                                const float* __restrict__ p2, const float* __restrict__ boxc,
                                                const float* __restrict__ gtb, const int* __restrict__ gtl,
                                                unsigned* __restrict__ maskg){
    __shared__ float metric[MAXC];
    __shared__ int   candn[MAXC];
    __shared__ float rv[4]; __shared__ int ri[4];
    __shared__ float sbest;
    int g = blockIdx.x, b = blockIdx.y, tid = threadIdx.x;
    const float* gb = gtb + ((size_t)b*NG + g)*4;
    float gx1=gb[0], gy1=gb[1], gx2=gb[2], gy2=gb[3];
    int label = gtl[b*NG+g];
    const float* bx1 = boxc + (size_t)b*NA;
    const float* by1 = bx1 + (size_t)NB*NA;
    const float* bx2 = by1 + (size_t)NB*NA;
    const float* by2 = bx2 + (size_t)NB*NA;

    int xs[3], ys[3], nxv[3], cc[3];
    #pragma unroll
    for(int lvl=0; lvl<3; lvl++){
        float s = (float)(8<<lvl); int D = 80>>lvl;
        int x0 = max(0, (int)floorf(gx1/s - 0.5f));
        int x1 = min(D-1, (int)ceilf (gx2/s - 0.5f));
        int y0 = max(0, (int)floorf(gy1/s - 0.5f));
        int y1 = min(D-1, (int)ceilf (gy2/s - 0.5f));
        xs[lvl]=x0; ys[lvl]=y0;
        nxv[lvl]=max(0, x1-x0+1);
        int nyv=max(0, y1-y0+1);
        cc[lvl]=nxv[lvl]*nyv;
    }
    int t0 = cc[0], t01 = cc[0]+cc[1], total = t01+cc[2];

    for(int c=tid; c<total; c+=256){
        int lvl, rel;
        if(c < t0){ lvl=0; rel=c; }
        else if(c < t01){ lvl=1; rel=c-t0; }
        else { lvl=2; rel=c-t01; }
        int yy = ys[lvl] + rel / nxv[lvl];
        int xx = xs[lvl] + rel % nxv[lvl];
        int D = 80>>lvl; float s = (float)(8<<lvl);
        int off = (lvl==0)?0:((lvl==1)?HW0:(HW0+HW1));
        int n = off + yy*D + xx;
        float cx = (xx+0.5f)*s, cy = (yy+0.5f)*s;
        float met = 0.f;
        if((cx>gx1)&&(cx<gx2)&&(cy>gy1)&&(cy<gy2)){
            float ov = iou_gp(gx1,gy1,gx2,gy2, bx1[n],by1[n],bx2[n],by2[n]);
            int m,hw; const float* base = level_base(p0,p1,p2,b,n,m,hw);
            float x = base[(size_t)(4*BINS+label)*hw + m];
            float sg = 1.f/(1.f+__expf(-x));
            float o2 = ov*ov;
            met = sqrtf(sg)*(o2*o2*o2);
        }
        metric[c] = met; candn[c] = n;
    }
    __syncthreads();

    for(int k=0;k<TOPKK;k++){
        float bv = -1.f; int bi = 0x7fffffff;
        for(int c=tid; c<total; c+=256){
            float v = metric[c];
            if(v > bv){ bv=v; bi=c; }           // ascending scan keeps lowest candidate idx
        }
        #pragma unroll
        for(int o=1; o<64; o<<=1){
            float ov = __shfl_xor(bv, o);
            int   oi = __shfl_xor(bi, o);
            if(ov > bv || (ov == bv && oi < bi)){ bv=ov; bi=oi; }
        }
        if((tid&63)==0){ rv[tid>>6]=bv; ri[tid>>6]=bi; }
        __syncthreads();
        if(tid==0){
            float fb=rv[0]; int fi=ri[0];
            #pragma unroll
            for(int w=1; w<4; w++)
                if(rv[w]>fb || (rv[w]==fb && ri[w]<fi)){ fb=rv[w]; fi=ri[w]; }
            sbest = fb;
            if(fb > EPSF){
                metric[fi] = -1.f;
                atomicOr(&maskg[(size_t)b*NA + candn[fi]], 1u<<g);
            }
        }
        __syncthreads();
        if(sbest <= EPSF) break;                // uniform
    }
}

// ------- kernel 3: resolve + fg compaction (ballot, one atomic per block) -------
__global__ __launch_bounds__(256) void k_resolve(const float* __restrict__ p0, const float* __restrict__ p1,
                                                 const float* __restrict__ p2, const float* __restrict__ boxc,
                                                 const float* __restrict__ gtb, const int* __restrict__ gtl,
                                                 const unsigned* __restrict__ maskg,
                                                 float* __restrict__ amax, float* __restrict__ omax,
                                                 int* __restrict__ cnt, unsigned* __restrict__ fglist,
                                                 float* __restrict__ fgalign, float* __restrict__ fgx){
    __shared__ float sgt[NG*4];
    __shared__ int wcnt[4];
    __shared__ int sbase;
    int tid = threadIdx.x; int b = blockIdx.y;
    int wv = tid >> 6, lane = tid & 63;
    if(tid < NG*4) sgt[tid] = gtb[(size_t)b*NG*4 + tid];
    __syncthreads();
    int n = blockIdx.x*256 + tid;
    size_t bn = (size_t)b*NA + n;
    unsigned mask = (n < NA) ? maskg[bn] : 0u;
    bool fg = (mask != 0u);

    int match = 0; float ov = 0.f, av = 0.f, x = 0.f;
    if(fg){
        float px1 = boxc[bn], py1 = boxc[(size_t)NB*NA+bn],
              px2 = boxc[2*(size_t)NB*NA+bn], py2 = boxc[3*(size_t)NB*NA+bn];
        if(__popc(mask) > 1){
            float best = -1.f; int bi = 0;
            for(int g=0; g<NG; g++){
                float o = iou_gp(sgt[g*4],sgt[g*4+1],sgt[g*4+2],sgt[g*4+3],px1,py1,px2,py2);
                if(o > best){ best=o; bi=g; }   // strict > : first max == jnp.argmax
            }
            match = bi; ov = best;
        } else {
            match = __ffs(mask)-1;
            ov = iou_gp(sgt[match*4],sgt[match*4+1],sgt[match*4+2],sgt[match*4+3],px1,py1,px2,py2);
        }
        int label = gtl[b*NG+match];
        int m,hw; const float* base = level_base(p0,p1,p2,b,n,m,hw);
        x = base[(size_t)(4*BINS+label)*hw + m];
        float sg = 1.f/(1.f+__expf(-x));
        float ov2 = ov*ov;
        av = sqrtf(sg)*(ov2*ov2*ov2);
        atomicMax((int*)&amax[b*NG+match], __float_as_int(av));
        atomicMax((int*)&omax[b*NG+match], __float_as_int(ov));
    }
    unsigned long long bal = __ballot(fg);
    if(lane==0) wcnt[wv] = __popcll(bal);
    __syncthreads();
    if(tid==0){
        int tot = wcnt[0]+wcnt[1]+wcnt[2]+wcnt[3];
        sbase = tot ? atomicAdd(cnt, tot) : 0;
    }
    __syncthreads();
    if(fg){
        int woff = 0;
        for(int w=0; w<wv; w++) woff += wcnt[w];
        int before = __popcll(bal & ((1ull<<lane)-1ull));
        int pos = sbase + woff + before;
        fglist[pos]  = (unsigned)bn | ((unsigned)match << 18);
        fgalign[pos] = av;
        fgx[pos]     = x;
    }
}

// ------- kernel 4: fg anchors — THREAD per anchor, 2 logit loads per side via precomputed lse -------
__global__ __launch_bounds__(256) void k_fg(const float* __restrict__ p0, const float* __restrict__ p1,
                                            const float* __restrict__ p2, const float* __restrict__ boxc,
                                            const float* __restrict__ lsev, const float* __restrict__ gtb,
                                            const float* __restrict__ amax, const float* __restrict__ omax,
                                            const int* __restrict__ cnt, const unsigned* __restrict__ fglist,
                                            const float* __restrict__ fgalign, const float* __restrict__ fgx,
                                            float* __restrict__ piou, float* __restrict__ pdfl,
                                            float* __restrict__ pfix){
    __shared__ float siou[4], sdfl[4], sfix[4];
    int tid = threadIdx.x, wv = tid>>6, lane = tid&63;
    int i = blockIdx.x*256 + tid;
    float iou_l = 0.f, dfl_l = 0.f, fix_l = 0.f;
    if(i < *cnt){
        unsigned e = fglist[i];
        int bn = e & 0x3FFFF;
        int g  = e >> 18;
        int b  = bn / NA;
        int n  = bn - b*NA;
        float align = fgalign[i];
        float norm = align * omax[b*NG+g] / (amax[b*NG+g] + EPSF);
        const float* gb = gtb + ((size_t)b*NG+g)*4;
        float tx1=gb[0], ty1=gb[1], tx2=gb[2], ty2=gb[3];
        float px1 = boxc[bn], py1 = boxc[(size_t)NB*NA+bn],
              px2 = boxc[2*(size_t)NB*NA+bn], py2 = boxc[3*(size_t)NB*NA+bn];
        int m,hw; const float* base = level_base(p0,p1,p2,b,n,m,hw);
        float cx,cy,st; anchor_geom(n,cx,cy,st);
        // ---- DFL via precomputed lse + 2 logits per side ----
        float dt4[4] = { cx-tx1, cy-ty1, tx2-cx, ty2-cy };
        #pragma unroll
        for(int j=0;j<4;j++){
            float d = fminf(fmaxf(dt4[j],0.f)/st, 14.999999f);
            float lo = floorf(d); float a = d-lo;
            int li = (int)lo; int ui = min(li+1, BINS-1);
            float lse = lsev[(size_t)j*NB*NA + bn];
            float xlo = base[(size_t)(j*BINS+li)*hw + m];
            float xup = base[(size_t)(j*BINS+ui)*hw + m];
            dfl_l += -((1.f-a)*(xlo-lse) + a*(xup-lse));
        }
        // ---- CIoU ----
        float w1=px2-px1, h1=py2-py1, w2=tx2-tx1, h2=ty2-ty1;
        float inter = fmaxf(fminf(px2,tx2)-fmaxf(px1,tx1),0.f) *
                      fmaxf(fminf(py2,ty2)-fmaxf(py1,ty1),0.f);
        float uni = w1*h1 + w2*h2 - inter + EPSF;
        float iou = inter/uni;
        float cwd = fmaxf(px2,tx2)-fminf(px1,tx1);
        float chd = fmaxf(py2,ty2)-fminf(py1,ty1);
        float c2 = cwd*cwd + chd*chd + EPSF;
        float dx = px1+px2-tx1-tx2, dy = py1+py2-ty1-ty2;
        float rho2 = (dx*dx + dy*dy)*0.25f;
        float dv = atanf(w2/(h2+EPSF)) - atanf(w1/(h1+EPSF));
        float v = 0.40528473456935108577f*dv*dv;   // 4/pi^2
        float alpha = v/(v - iou + 1.f + EPSF);
        iou_l = 1.f - (iou - rho2/c2 - v*alpha);
        // ---- focal correction: full(x, t=norm) - f0(x) ----
        float fx = fgx[i];
        float p, ce0;
        float f0 = focal0(fx, p, ce0);
        float tv = norm;
        float cet = ce0 - fx*tv;
        float pt = p*tv + (1.f-p)*(1.f-tv);
        float at = 0.25f*tv + 0.75f*(1.f-tv);
        float om = 1.f-pt;
        fix_l = at*om*om*cet - f0;
    }
    #pragma unroll
    for(int o=32; o; o>>=1){
        iou_l += __shfl_down(iou_l, o);
        dfl_l += __shfl_down(dfl_l, o);
        fix_l += __shfl_down(fix_l, o);
    }
    if(lane==0){ siou[wv]=iou_l; sdfl[wv]=dfl_l; sfix[wv]=fix_l; }
    __syncthreads();
    if(tid==0){
        piou[blockIdx.x] = siou[0]+siou[1]+siou[2]+siou[3];
        pdfl[blockIdx.x] = sdfl[0]+sdfl[1]+sdfl[2]+sdfl[3];
        pfix[blockIdx.x] = sfix[0]+sfix[1]+sfix[2]+sfix[3];
    }
}

// ------- kernel 5: final reduce + weights -------
__global__ __launch_bounds__(256) void k_final(const float* __restrict__ pcls, const float* __restrict__ piou,
                                               const float* __restrict__ pdfl, const float* __restrict__ pfix,
                                               const int* __restrict__ cnt, float* __restrict__ out){
    __shared__ float sa[4], sb[4], sc[4], sd[4];
    int tid = threadIdx.x, wv = tid>>6, lane = tid&63;
    float A = 0.f, B = 0.f, C = 0.f, D = 0.f;
    for(int t=tid; t<FOCAL_BLOCKS; t+=256) A += pcls[t];
    if(tid < FGB2){ B = piou[tid]; C = pdfl[tid]; D = pfix[tid]; }
    #pragma unroll
    for(int o=32; o; o>>=1){
        A += __shfl_down(A, o);
        B += __shfl_down(B, o);
        C += __shfl_down(C, o);
        D += __shfl_down(D, o);
    }
    if(lane==0){ sa[wv]=A; sb[wv]=B; sc[wv]=C; sd[wv]=D; }
    __syncthreads();
    if(tid==0){
        float a  = sa[0]+sa[1]+sa[2]+sa[3];
        float bb = sb[0]+sb[1]+sb[2]+sb[3];
        float cc = sc[0]+sc[1]+sc[2]+sc[3];
        float dd = sd[0]+sd[1]+sd[2]+sd[3];
        int c = *cnt;
        float den = (float)(c > 1 ? c : 1);
        out[0] = 7.5f * bb / den;
        out[1] = 1.5f * cc / den;
        out[2] = 0.5f * (a + dd) / den;
    }
}

extern "C" void kernel_launch(void* const* d_in, const int* in_sizes, int n_in,
                              void* d_out, int out_size, void* d_ws, size_t ws_size,
                              hipStream_t stream) {
    (void)in_sizes; (void)n_in; (void)out_size; (void)ws_size;
    const float* p0  = (const float*)d_in[0];
    const float* p1  = (const float*)d_in[1];
    const float* p2  = (const float*)d_in[2];
    const float* gtb = (const float*)d_in[3];
    const int*   gtl = (const int*)d_in[4];
    float* out = (float*)d_out;

    char* ws = (char*)d_ws;
    const size_t COMP = (size_t)NB*NA*4;          // 537600 B
    size_t off = 0;
    int*      cnt    = (int*)     (ws + off); off += 16;
    float*    amax   = (float*)   (ws + off); off += NB*NG*4;       // 2048
    float*    omax   = (float*)   (ws + off); off += NB*NG*4;
    unsigned* maskg  = (unsigned*)(ws + off); off += COMP;
    float*    boxc   = (float*)   (ws + off); off += 4*COMP;        // SoA x1,y1,x2,y2
    float*    lsev   = (float*)   (ws + off); off += 4*COMP;        // per (j,b,n) log-sum-exp
    unsigned* fglist = (unsigned*)(ws + off); off += MAXFG*4;
    float*    fgalign= (float*)   (ws + off); off += MAXFG*4;
    float*    fgx    = (float*)   (ws + off); off += MAXFG*4;
    float*    pcls   = (float*)   (ws + off); off += FOCAL_BLOCKS*4;
    float*    piou   = (float*)   (ws + off); off += FGB2*4;
    float*    pdfl   = (float*)   (ws + off); off += FGB2*4;
    float*    pfix   = (float*)   (ws + off); off += FGB2*4;

    dim3 blk(256);
    k_main   <<<MAIN_BLOCKS,   blk, 0, stream>>>(p0,p1,p2, boxc, lsev, maskg, amax, omax, cnt, pcls);
    k_assign <<<dim3(NG,NB),   blk, 0, stream>>>(p0,p1,p2, boxc, gtb, gtl, maskg);
    k_resolve<<<dim3(33,NB),   blk, 0, stream>>>(p0,p1,p2, boxc, gtb, gtl, maskg,
                                                 amax, omax, cnt, fglist, fgalign, fgx);
    k_fg     <<<FGB2,          blk, 0, stream>>>(p0,p1,p2, boxc, lsev, gtb, amax, omax,
                                                 cnt, fglist, fgalign, fgx, piou, pdfl, pfix);
    k_final  <<<1,             blk, 0, stream>>>(pcls, piou, pdfl, pfix, cnt, out);
}